// Round 3
// baseline (1854.812 us; speedup 1.0000x reference)
//
#include <hip/hip_runtime.h>

#define T_DIM 1024
#define B_DIM 512
#define OBS_DIM 64
#define H_DIM 128
#define G3 384
#define A_DIM 16
#define CT 128
#define NCHUNK 8

typedef __bf16 bf16;
typedef __attribute__((ext_vector_type(8))) __bf16 bf16x8;
typedef __attribute__((ext_vector_type(4))) float f32x4;

#define MFMA(a, b, c) __builtin_amdgcn_mfma_f32_16x16x32_bf16((a), (b), (c), 0, 0, 0)

// lgkm-only barrier: __syncthreads() drains vmcnt(0) too, serializing in-flight
// global prefetches/stores into the scan's critical path. All cross-thread data
// here moves through LDS.
#define LGKM_BARRIER() asm volatile("s_waitcnt lgkmcnt(0)\n\ts_barrier" ::: "memory")

__device__ __forceinline__ float sigm(float x) { return 1.0f / (1.0f + __expf(-x)); }
__device__ __forceinline__ float tanh_f(float x) { return 1.0f - 2.0f / (__expf(2.0f * x) + 1.0f); }

// Gate-column permutation: new col c -> orig col. Window w = c/96 covers
// h-indices [w*32, w*32+32); within window: [r(32) | z(32) | n(32)].
// orig = gate*128 + w*32 + s.

// ---------------- prep: permuted bf16 weights + h_state init ----------------
__global__ __launch_bounds__(256) void prep_k(
    const float* __restrict__ hidden, const int* __restrict__ dones,
    const float* __restrict__ W_emb, const float* __restrict__ Wi,
    const float* __restrict__ bi, const float* __restrict__ Wh,
    const float* __restrict__ Wa1, const float* __restrict__ Wa2,
    const float* __restrict__ Wc1, const float* __restrict__ Wc2,
    bf16* __restrict__ wembT, bf16* __restrict__ wiT, bf16* __restrict__ whT,
    bf16* __restrict__ wa1T, bf16* __restrict__ wa2T, bf16* __restrict__ wc1T,
    bf16* __restrict__ wc2T, float* __restrict__ bi_p, float* __restrict__ h_state) {
  int i = blockIdx.x * 256 + threadIdx.x;
  if (i < 8192) { int n = i / OBS_DIM, k = i % OBS_DIM; wembT[i] = (bf16)W_emb[k * H_DIM + n]; return; }
  i -= 8192;
  if (i < 49152) {
    int c = i / H_DIM, k = i % H_DIM;
    int w = c / 96, rem = c % 96;
    int oc = (rem / 32) * H_DIM + w * 32 + (rem & 31);
    wiT[i] = (bf16)Wi[k * G3 + oc]; return;
  }
  i -= 49152;
  if (i < 49152) {
    int c = i / H_DIM, k = i % H_DIM;
    int w = c / 96, rem = c % 96;
    int oc = (rem / 32) * H_DIM + w * 32 + (rem & 31);
    whT[i] = (bf16)Wh[k * G3 + oc]; return;
  }
  i -= 49152;
  if (i < 16384) { int n = i / H_DIM, k = i % H_DIM; wa1T[i] = (bf16)Wa1[k * H_DIM + n]; return; }
  i -= 16384;
  if (i < 2048) { int a = i / H_DIM, k = i % H_DIM; wa2T[i] = (bf16)Wa2[k * A_DIM + a]; return; }
  i -= 2048;
  if (i < 16384) { int n = i / H_DIM, k = i % H_DIM; wc1T[i] = (bf16)Wc1[k * H_DIM + n]; return; }
  i -= 16384;
  if (i < 2048) { int r = i / H_DIM, k = i % H_DIM; wc2T[i] = (r == 0) ? (bf16)Wc2[k] : (bf16)0.0f; return; }
  i -= 2048;
  if (i < 384) {
    int w = i / 96, rem = i % 96;
    int oc = (rem / 32) * H_DIM + w * 32 + (rem & 31);
    bi_p[i] = bi[oc]; return;
  }
  i -= 384;
  if (i < 65536) { int b = i / H_DIM; h_state[i] = dones[b] ? 0.0f : hidden[i]; return; }
}

// ---------------- phase1: xi = relu(obs@W_emb+b_emb)@Wi_perm + bi_perm -------
__global__ __launch_bounds__(256) void phase1_k(
    const float* __restrict__ obs, const float* __restrict__ b_emb,
    const float* __restrict__ bi_p, const bf16* __restrict__ wembT,
    const bf16* __restrict__ wiT, bf16* __restrict__ xi, int row_base) {
  __shared__ __align__(16) bf16 lds[4][16][392];  // per-wave strip, padded stride
  int tid = threadIdx.x;
  int wave = tid >> 6, lane = tid & 63;
  int nl = lane & 15, q = lane >> 4;
  int r0 = blockIdx.x * 64 + wave * 16;          // chunk-local row
  long grow = (long)row_base + r0 + nl;          // global row for A loads

  // A fragments from obs (f32 -> bf16)
  bf16x8 ao[2];
  const float* op = obs + grow * OBS_DIM;
#pragma unroll
  for (int kb = 0; kb < 2; ++kb) {
    float4 v0 = *(const float4*)(op + kb * 32 + q * 8);
    float4 v1 = *(const float4*)(op + kb * 32 + q * 8 + 4);
    bf16x8 f;
    f[0] = (bf16)v0.x; f[1] = (bf16)v0.y; f[2] = (bf16)v0.z; f[3] = (bf16)v0.w;
    f[4] = (bf16)v1.x; f[5] = (bf16)v1.y; f[6] = (bf16)v1.z; f[7] = (bf16)v1.w;
    ao[kb] = f;
  }
  // emb = relu(obs@W_emb + b_emb) -> LDS strip [16][128]
#pragma unroll
  for (int nt = 0; nt < 8; ++nt) {
    f32x4 c = {0.f, 0.f, 0.f, 0.f};
#pragma unroll
    for (int kb = 0; kb < 2; ++kb) {
      bf16x8 bfr = *(const bf16x8*)(wembT + (nt * 16 + nl) * OBS_DIM + kb * 32 + q * 8);
      c = MFMA(ao[kb], bfr, c);
    }
    float be = b_emb[nt * 16 + nl];
#pragma unroll
    for (int r = 0; r < 4; ++r) {
      float v = c[r] + be;
      lds[wave][q * 4 + r][nt * 16 + nl] = (bf16)(v > 0.f ? v : 0.f);
    }
  }
  // reload emb as A fragments
  bf16x8 ae[4];
#pragma unroll
  for (int kb = 0; kb < 4; ++kb) ae[kb] = *(const bf16x8*)&lds[wave][nl][kb * 32 + q * 8];

  // xi = emb@Wi_perm + bi_perm -> LDS strip [16][384]
#pragma unroll
  for (int nt = 0; nt < 24; ++nt) {
    f32x4 c = {0.f, 0.f, 0.f, 0.f};
#pragma unroll
    for (int kb = 0; kb < 4; ++kb) {
      bf16x8 bfr = *(const bf16x8*)(wiT + (nt * 16 + nl) * H_DIM + kb * 32 + q * 8);
      c = MFMA(ae[kb], bfr, c);
    }
    float bv = bi_p[nt * 16 + nl];
#pragma unroll
    for (int r = 0; r < 4; ++r) lds[wave][q * 4 + r][nt * 16 + nl] = (bf16)(c[r] + bv);
  }
  // coalesced strip copy to global (16 rows x 384 bf16 contiguous = 12 KiB)
  bf16* dst = xi + (long)r0 * G3;
#pragma unroll
  for (int it = 0; it < 12; ++it) {
    int e0 = (it * 64 + lane) * 8;
    int row = e0 / G3, col = e0 % G3;
    *(int4*)(dst + e0) = *(const int4*)&lds[wave][row][col];
  }
}

// ---------------- scan: GRU, 1 chain per block, grid 512, 1 barrier/step -----
__global__ __launch_bounds__(256, 2) void scan_k(
    const bf16* __restrict__ xi, const int* __restrict__ dones,
    const float* __restrict__ bh_n, const bf16* __restrict__ whT,
    float* __restrict__ h_state, bf16* __restrict__ y,
    float* __restrict__ hidden_out, int chunk) {
  __shared__ __align__(16) bf16 h_lds[2][136];   // row0 = h, row1 = zeros (broadcast row)
  __shared__ __align__(16) bf16 xibuf[2][8][G3]; // double-buffered 8-step xi
  __shared__ int dn[CT + 1];
  int tid = threadIdx.x;
  int wave = tid >> 6, lane = tid & 63;
  int nl = lane & 15, q = lane >> 4;
  int b = blockIdx.x;

  if (tid < 272) ((bf16*)h_lds)[tid] = (bf16)0.0f;
  if (tid < 128) h_lds[0][tid] = (bf16)h_state[b * H_DIM + tid];  // same-thread order ok
  for (int i = tid; i <= CT; i += 256) {
    int t = chunk * CT + i;
    dn[i] = (t < T_DIM) ? dones[t * B_DIM + b] : 0;
  }
  // per-lane gate state (meaningful in q==0 lanes; window w = wave)
  int g_a = wave * 32 + nl, g_b = g_a + 16;
  float hA = h_state[b * H_DIM + g_a];
  float hB = h_state[b * H_DIM + g_b];
  float bhnA = bh_n[g_a], bhnB = bh_n[g_b];

  // Wh B-fragments, register-stationary (permuted: wave w owns cols [w*96,w*96+96))
  bf16x8 wf[6][4];
#pragma unroll
  for (int j = 0; j < 6; ++j)
#pragma unroll
    for (int kb = 0; kb < 4; ++kb)
      wf[j][kb] = *(const bf16x8*)(whT + ((wave * 6 + j) * 16 + nl) * H_DIM + kb * 32 + q * 8);

  // stage first 8 steps of xi
  for (int i = tid; i < 384; i += 256) {
    int tt = i / 48, pos = i % 48;
    *(int4*)&xibuf[0][tt][pos * 8] = *(const int4*)(xi + ((long)tt * B_DIM + b) * G3 + pos * 8);
  }
  LGKM_BARRIER();

  const bf16* hrow = (nl == 0) ? h_lds[0] : h_lds[1];  // rows 1..15 of A read zeros (broadcast)
  int cur = 0;
  for (int tb = 0; tb < CT; tb += 8) {
    int4 pf0, pf1;
    bool hv = (tb + 8) < CT;
    if (hv) {
      int i0 = tid, i1 = 256 + tid;
      pf0 = *(const int4*)(xi + ((long)(tb + 8 + i0 / 48) * B_DIM + b) * G3 + (i0 % 48) * 8);
      if (tid < 128)
        pf1 = *(const int4*)(xi + ((long)(tb + 8 + i1 / 48) * B_DIM + b) * G3 + (i1 % 48) * 8);
    }
#pragma unroll
    for (int ts = 0; ts < 8; ++ts) {
      int t = tb + ts;
      // gate-side xi reads (independent of MFMA; latency hidden behind it)
      float xrA = (float)xibuf[cur][ts][wave * 96 + nl];
      float xrB = (float)xibuf[cur][ts][wave * 96 + 16 + nl];
      float xzA = (float)xibuf[cur][ts][wave * 96 + 32 + nl];
      float xzB = (float)xibuf[cur][ts][wave * 96 + 48 + nl];
      float xnA = (float)xibuf[cur][ts][wave * 96 + 64 + nl];
      float xnB = (float)xibuf[cur][ts][wave * 96 + 80 + nl];
      int rst = dn[t + 1];
      bf16x8 ha[4];
#pragma unroll
      for (int kb = 0; kb < 4; ++kb) ha[kb] = *(const bf16x8*)(hrow + kb * 32 + q * 8);
      f32x4 c[6];
#pragma unroll
      for (int j = 0; j < 6; ++j) c[j] = (f32x4){0.f, 0.f, 0.f, 0.f};
#pragma unroll
      for (int kb = 0; kb < 4; ++kb)
#pragma unroll
        for (int j = 0; j < 6; ++j) c[j] = MFMA(ha[kb], wf[j][kb], c[j]);
      if (q == 0) {
        // tiles: 0,1 = r(g_a,g_b); 2,3 = z; 4,5 = n — all in row 0 (the chain)
        float rA = sigm(xrA + c[0][0]);
        float rB = sigm(xrB + c[1][0]);
        float zA = sigm(xzA + c[2][0]);
        float zB = sigm(xzB + c[3][0]);
        float nA = tanh_f(xnA + rA * (c[4][0] + bhnA));
        float nB = tanh_f(xnB + rB * (c[5][0] + bhnB));
        float newA = (1.f - zA) * nA + zA * hA;
        float newB = (1.f - zB) * nB + zB * hB;
        bf16* yp = y + ((long)t * B_DIM + b) * H_DIM;
        yp[g_a] = (bf16)newA;
        yp[g_b] = (bf16)newB;
        if (chunk == NCHUNK - 1 && t == CT - 1) {
          hidden_out[b * H_DIM + g_a] = newA;
          hidden_out[b * H_DIM + g_b] = newB;
        }
        hA = rst ? 0.f : newA;   // reset applied for NEXT step
        hB = rst ? 0.f : newB;
        h_lds[0][g_a] = (bf16)hA;
        h_lds[0][g_b] = (bf16)hB;
      }
      LGKM_BARRIER();
    }
    if (hv) {
      int nb = cur ^ 1;
      {
        int i0 = tid;
        *(int4*)&xibuf[nb][i0 / 48][(i0 % 48) * 8] = pf0;
        if (tid < 128) {
          int i1 = 256 + tid;
          *(int4*)&xibuf[nb][i1 / 48][(i1 % 48) * 8] = pf1;
        }
      }
      LGKM_BARRIER();
      cur = nb;
    }
  }
  if (q == 0) {
    h_state[b * H_DIM + g_a] = hA;
    h_state[b * H_DIM + g_b] = hB;
  }
}

// ---------------- heads: actor + critic from y (bf16 MFMA) -------------------
__global__ __launch_bounds__(256) void heads_k(
    const bf16* __restrict__ y, const float* __restrict__ ba1,
    const float* __restrict__ ba2, const float* __restrict__ bc1,
    const float* __restrict__ bc2, const bf16* __restrict__ wa1T,
    const bf16* __restrict__ wa2T, const bf16* __restrict__ wc1T,
    const bf16* __restrict__ wc2T, float* __restrict__ logits,
    float* __restrict__ v, int t_base) {
  __shared__ __align__(16) bf16 s_a1[4][16][136];
  __shared__ __align__(16) float s_o[4][16][16];
  __shared__ __align__(16) float s_v[4][16];
  int tid = threadIdx.x, wave = tid >> 6, lane = tid & 63;
  int nl = lane & 15, q = lane >> 4;
  int r0 = blockIdx.x * 64 + wave * 16;          // chunk-local row
  long gr0 = (long)t_base * B_DIM + r0;          // global row

  bf16x8 ya[4];
#pragma unroll
  for (int kb = 0; kb < 4; ++kb)
    ya[kb] = *(const bf16x8*)(y + (long)(r0 + nl) * H_DIM + kb * 32 + q * 8);

  // actor layer 1
#pragma unroll
  for (int nt = 0; nt < 8; ++nt) {
    f32x4 c = {0.f, 0.f, 0.f, 0.f};
#pragma unroll
    for (int kb = 0; kb < 4; ++kb) {
      bf16x8 bfr = *(const bf16x8*)(wa1T + (nt * 16 + nl) * H_DIM + kb * 32 + q * 8);
      c = MFMA(ya[kb], bfr, c);
    }
    float bv = ba1[nt * 16 + nl];
#pragma unroll
    for (int r = 0; r < 4; ++r) {
      float val = c[r] + bv;
      s_a1[wave][q * 4 + r][nt * 16 + nl] = (bf16)(val > 0.f ? val : 0.f);
    }
  }
  bf16x8 a1f[4];
#pragma unroll
  for (int kb = 0; kb < 4; ++kb) a1f[kb] = *(const bf16x8*)&s_a1[wave][nl][kb * 32 + q * 8];
  // logits
  {
    f32x4 c = {0.f, 0.f, 0.f, 0.f};
#pragma unroll
    for (int kb = 0; kb < 4; ++kb) {
      bf16x8 bfr = *(const bf16x8*)(wa2T + nl * H_DIM + kb * 32 + q * 8);
      c = MFMA(a1f[kb], bfr, c);
    }
    float bv = ba2[nl];
#pragma unroll
    for (int r = 0; r < 4; ++r) s_o[wave][q * 4 + r][nl] = c[r] + bv;
  }
  // critic layer 1
#pragma unroll
  for (int nt = 0; nt < 8; ++nt) {
    f32x4 c = {0.f, 0.f, 0.f, 0.f};
#pragma unroll
    for (int kb = 0; kb < 4; ++kb) {
      bf16x8 bfr = *(const bf16x8*)(wc1T + (nt * 16 + nl) * H_DIM + kb * 32 + q * 8);
      c = MFMA(ya[kb], bfr, c);
    }
    float bv = bc1[nt * 16 + nl];
#pragma unroll
    for (int r = 0; r < 4; ++r) {
      float val = c[r] + bv;
      s_a1[wave][q * 4 + r][nt * 16 + nl] = (bf16)(val > 0.f ? val : 0.f);
    }
  }
  bf16x8 c1f[4];
#pragma unroll
  for (int kb = 0; kb < 4; ++kb) c1f[kb] = *(const bf16x8*)&s_a1[wave][nl][kb * 32 + q * 8];
  // v (Wc2 padded to 16 cols, col 0 real)
  {
    f32x4 c = {0.f, 0.f, 0.f, 0.f};
#pragma unroll
    for (int kb = 0; kb < 4; ++kb) {
      bf16x8 bfr = *(const bf16x8*)(wc2T + nl * H_DIM + kb * 32 + q * 8);
      c = MFMA(c1f[kb], bfr, c);
    }
    if (nl == 0) {
      float bv = bc2[0];
#pragma unroll
      for (int r = 0; r < 4; ++r) s_v[wave][q * 4 + r] = c[r] + bv;
    }
  }
  // coalesced writes
  *(int4*)(logits + gr0 * A_DIM + lane * 4) = *(const int4*)&s_o[wave][lane >> 2][(lane & 3) * 4];
  if (lane < 16) v[gr0 + lane] = s_v[wave][lane];
}

// ---------------- launch ------------------------------------------------------
extern "C" void kernel_launch(void* const* d_in, const int* in_sizes, int n_in,
                              void* d_out, int out_size, void* d_ws, size_t ws_size,
                              hipStream_t stream) {
  const float* hidden = (const float*)d_in[0];
  const float* obs    = (const float*)d_in[1];
  const int*   dones  = (const int*)d_in[2];
  const float* W_emb  = (const float*)d_in[3];
  const float* b_emb  = (const float*)d_in[4];
  const float* Wi     = (const float*)d_in[5];
  const float* bi     = (const float*)d_in[6];
  const float* Wh     = (const float*)d_in[7];
  const float* bh_n   = (const float*)d_in[8];
  const float* Wa1    = (const float*)d_in[9];
  const float* ba1    = (const float*)d_in[10];
  const float* Wa2    = (const float*)d_in[11];
  const float* ba2    = (const float*)d_in[12];
  const float* Wc1    = (const float*)d_in[13];
  const float* bc1    = (const float*)d_in[14];
  const float* Wc2    = (const float*)d_in[15];
  const float* bc2    = (const float*)d_in[16];

  float* out_hidden = (float*)d_out;
  float* out_logits = out_hidden + B_DIM * H_DIM;
  float* out_v      = out_logits + (long)T_DIM * B_DIM * A_DIM;

  char* ws = (char*)d_ws;
  bf16*  wembT   = (bf16*)(ws + 0);
  bf16*  wiT     = (bf16*)(ws + 16384);
  bf16*  whT     = (bf16*)(ws + 114688);
  bf16*  wa1T    = (bf16*)(ws + 212992);
  bf16*  wa2T    = (bf16*)(ws + 245760);
  bf16*  wc1T    = (bf16*)(ws + 249856);
  bf16*  wc2T    = (bf16*)(ws + 282624);
  float* bi_p    = (float*)(ws + 286720);
  float* h_state = (float*)(ws + 288256);
  bf16*  xi      = (bf16*)(ws + 550400);     // CT*B*384 bf16 = 50.3 MB
  bf16*  yb      = (bf16*)(ws + 50882048);   // CT*B*128 bf16 = 16.8 MB; total 67.7 MB

  prep_k<<<818, 256, 0, stream>>>(hidden, dones, W_emb, Wi, bi, Wh, Wa1, Wa2, Wc1, Wc2,
                                  wembT, wiT, whT, wa1T, wa2T, wc1T, wc2T, bi_p, h_state);
  for (int c = 0; c < NCHUNK; ++c) {
    phase1_k<<<(CT * B_DIM) / 64, 256, 0, stream>>>(obs, b_emb, bi_p, wembT, wiT, xi,
                                                    c * CT * B_DIM);
    scan_k<<<B_DIM, 256, 0, stream>>>(xi, dones, bh_n, whT, h_state, yb,
                                      out_hidden, c);
    heads_k<<<(CT * B_DIM) / 64, 256, 0, stream>>>(yb, ba1, ba2, bc1, bc2, wa1T, wa2T,
                                                   wc1T, wc2T, out_logits, out_v, c * CT);
  }
  (void)in_sizes; (void)n_in; (void)out_size; (void)ws_size;
}